// Round 6
// baseline (267.289 us; speedup 1.0000x reference)
//
#include <hip/hip_runtime.h>
#include <stdint.h>

// Problem constants: B=8, S=1024, D=1024, H=16, DH=64
typedef __attribute__((ext_vector_type(8))) short short8;
typedef __attribute__((ext_vector_type(4))) float floatx4;

__device__ __forceinline__ unsigned short f2bf(float f) {
  union { float f; uint32_t u; } v; v.f = f;
  uint32_t u = v.u;
  return (unsigned short)((u + 0x7FFFu + ((u >> 16) & 1u)) >> 16);  // RNE
}

__device__ __forceinline__ uint32_t fbits(float f) {
  union { float f; uint32_t u; } v; v.f = f; return v.u;
}
// pack two fp32 -> [bf16(hi):bf16(lo)] in ONE v_perm_b32 (truncating round)
__device__ __forceinline__ uint32_t pkbf(float hi, float lo) {
  return __builtin_amdgcn_perm(fbits(hi), fbits(lo), 0x07060302u);
}

// async global->LDS, 16B per lane; LDS dest = wave-uniform base + lane*16
__device__ __forceinline__ void gl_lds16(const void* g, void* l) {
  __builtin_amdgcn_global_load_lds((__attribute__((address_space(1))) void*)g,
                                   (__attribute__((address_space(3))) void*)l,
                                   16, 0, 0);
}

// ------- fused prep: cast x->bf16 (blocks 0..8191) + transpose both weights -------
__global__ __launch_bounds__(256) void prep_kernel(const float* __restrict__ x,
                                                   unsigned short* __restrict__ xb,
                                                   const float* __restrict__ Wqkv,
                                                   unsigned short* __restrict__ WqkvT,
                                                   const float* __restrict__ Wout,
                                                   unsigned short* __restrict__ WoutT) {
  __shared__ float tile[32][33];  // +1 pad (transpose branch only)
  int id = blockIdx.x;
  if (id < 8192) {
    int i = id * 256 + threadIdx.x;
    float4 v = ((const float4*)x)[i];
    ushort4 o;
    o.x = f2bf(v.x); o.y = f2bf(v.y); o.z = f2bf(v.z); o.w = f2bf(v.w);
    ((ushort4*)xb)[i] = o;
    return;
  }
  id -= 8192;                      // 0..4095
  int bx = id & 127, r0 = (id >> 7) * 32;
  const int R = 1024;
  const float* in; unsigned short* out; int C;
  if (bx < 96) { in = Wqkv; out = WqkvT; C = 3072; }
  else         { in = Wout; out = WoutT; C = 1024; bx -= 96; }
  int c0 = bx * 32;
  int tx = threadIdx.x & 31;
  int ty = threadIdx.x >> 5;  // 0..7
  for (int i = ty; i < 32; i += 8)
    tile[i][tx] = in[(size_t)(r0 + i) * C + c0 + tx];
  __syncthreads();
  for (int i = ty; i < 32; i += 8)
    out[(size_t)(c0 + i) * R + r0 + tx] = f2bf(tile[tx][i]);
}

// ---------------- GEMM C[M,N] = A[M,1024] * Bt[N,1024]^T  (bf16 in, fp32 acc) -------
// 128x128 tile, BK=64, double-buffered global_load_lds staging, XOR-swizzled
// chunks, LDS-bounce coalesced epilogue. Proven structure: ~61 us QKV,
// MfmaUtil ~35% = this structure's ceiling (m97-ladder). 2D grid dim3(N/128, 64):
// consecutive blocks walk N sharing one A-panel — measured FETCH 77MB; every
// swizzle attempt (R3/R4) increased FETCH (200MB) and regressed. Do not re-swizzle.
__global__ __launch_bounds__(256) void gemm_bt_kernel(const unsigned short* __restrict__ A,
                                                      const unsigned short* __restrict__ Bt,
                                                      int N, int mode,
                                                      unsigned short* __restrict__ qo,
                                                      unsigned short* __restrict__ ko,
                                                      unsigned short* __restrict__ vo,
                                                      float* __restrict__ fo) {
  const int Kd = 1024;
  __shared__ union {
    struct { unsigned short A[2][8192]; unsigned short B[2][8192]; } s;  // 4x16KB
    float cf[16384];          // epilogue bounce, fp32 (64KB)
    unsigned short ch[32768]; // epilogue bounce, bf16 (first 32KB)
  } sm;
  const int tid = threadIdx.x;
  const int w = tid >> 6, lane = tid & 63;
  const int quad = lane >> 4, l16 = lane & 15;
  const int l7 = l16 & 7;
  const int wm = w >> 1, wn = w & 1;
  const int m0 = blockIdx.y * 128, n0 = blockIdx.x * 128;
  const int tr = (mode == 0) && (n0 >= 2048);  // all-V block: compute C^T
  const int r8 = lane >> 3, ch = lane & 7;
  const int sw = (ch ^ r8) * 8;  // swizzled k-chunk (elements) for staging

  floatx4 acc[4][4];
#pragma unroll
  for (int i = 0; i < 4; ++i)
#pragma unroll
    for (int j = 0; j < 4; ++j)
      acc[i][j] = (floatx4){0.f, 0.f, 0.f, 0.f};

  auto stage = [&](int it, int buf) {
    const int k0 = it * 64;
#pragma unroll
    for (int i = 0; i < 4; ++i) {
      const int row = i * 32 + w * 8 + r8;  // row&7 == r8
      gl_lds16(A + (size_t)(m0 + row) * Kd + k0 + sw, (char*)&sm.s.A[buf][0] + i * 4096 + w * 1024);
      gl_lds16(Bt + (size_t)(n0 + row) * Kd + k0 + sw, (char*)&sm.s.B[buf][0] + i * 4096 + w * 1024);
    }
  };

  stage(0, 0);
  __syncthreads();

  for (int it = 0; it < 16; ++it) {
    const int buf = it & 1;
    if (it < 15) stage(it + 1, buf ^ 1);  // async DMA, overlapped with compute(it)
    const char* Ab = (const char*)&sm.s.A[buf][0];
    const char* Bb = (const char*)&sm.s.B[buf][0];
#pragma unroll
    for (int half = 0; half < 2; ++half) {
      short8 af[4], bf[4];
#pragma unroll
      for (int i = 0; i < 4; ++i)
        af[i] = *(const short8*)(Ab + (wm * 64 + i * 16 + l16) * 128 +
                                 (((half << 2) | quad) ^ l7) * 16);
#pragma unroll
      for (int j = 0; j < 4; ++j)
        bf[j] = *(const short8*)(Bb + (wn * 64 + j * 16 + l16) * 128 +
                                 (((half << 2) | quad) ^ l7) * 16);
      if (!tr) {
#pragma unroll
        for (int i = 0; i < 4; ++i)
#pragma unroll
          for (int j = 0; j < 4; ++j)
            acc[i][j] = __builtin_amdgcn_mfma_f32_16x16x32_bf16(af[i], bf[j], acc[i][j], 0, 0, 0);
      } else {
#pragma unroll
        for (int p = 0; p < 4; ++p)
#pragma unroll
          for (int q = 0; q < 4; ++q)
            acc[p][q] = __builtin_amdgcn_mfma_f32_16x16x32_bf16(bf[p], af[q], acc[p][q], 0, 0, 0);
      }
    }
    __syncthreads();  // drains stage(it+1) DMA + guards buf reuse
  }

  // ---- LDS-bounce epilogue ----  C/D layout: col = lane&15, row = quad*4 + r
  if (mode == 1) {
    float* Cs = sm.cf;
#pragma unroll
    for (int i = 0; i < 4; ++i)
#pragma unroll
      for (int j = 0; j < 4; ++j)
#pragma unroll
        for (int r = 0; r < 4; ++r) {
          int row = wm * 64 + i * 16 + quad * 4 + r;
          int col = wn * 64 + j * 16 + l16;
          Cs[row * 128 + (col ^ ((row & 7) << 2))] = acc[i][j][r];
        }
    __syncthreads();
#pragma unroll
    for (int c = 0; c < 16; ++c) {
      int idx = c * 256 + tid;
      int row = idx >> 5, fc = idx & 31;
      float4 v = *(const float4*)&sm.cf[row * 128 + ((fc ^ (row & 7)) << 2)];
      *(float4*)&fo[(size_t)(m0 + row) * N + n0 + fc * 4] = v;
    }
  } else {
    unsigned short* Cs = sm.ch;
    if (!tr) {
#pragma unroll
      for (int i = 0; i < 4; ++i)
#pragma unroll
        for (int j = 0; j < 4; ++j)
#pragma unroll
          for (int r = 0; r < 4; ++r) {
            int row = wm * 64 + i * 16 + quad * 4 + r;
            int col = wn * 64 + j * 16 + l16;
            Cs[row * 128 + (col ^ ((row & 7) << 3))] = f2bf(acc[i][j][r]);
          }
    } else {
#pragma unroll
      for (int p = 0; p < 4; ++p)
#pragma unroll
        for (int q = 0; q < 4; ++q)
#pragma unroll
          for (int r = 0; r < 4; ++r) {
            int row = wn * 64 + p * 16 + quad * 4 + r;  // n-local
            int col = wm * 64 + q * 16 + l16;           // m-local
            Cs[row * 128 + (col ^ ((row & 7) << 3))] = f2bf(acc[p][q][r]);
          }
    }
    __syncthreads();
    unsigned short* dst0 = (n0 < 1024) ? qo : ko;  // used only when !tr
#pragma unroll
    for (int c = 0; c < 8; ++c) {
      int idx = c * 256 + tid;
      int row = idx >> 4, lc = idx & 15;
      short8 v = *(const short8*)&sm.ch[row * 128 + ((lc ^ (row & 7)) << 3)];
      int col = lc * 8;
      if (!tr) {
        int m = m0 + row, n = n0 + col;
        int h = (n & 1023) >> 6, dh = n & 63;
        int bb = m >> 10, s = m & 1023;
        *(short8*)&dst0[(size_t)(bb * 16 + h) * 65536 + (size_t)s * 64 + dh] = v;
      } else {
        int n = n0 + row, m = m0 + col;
        int h = (n & 1023) >> 6, dh = n & 63;
        int bb = m >> 10, s0 = m & 1023;
        *(short8*)&vo[(size_t)(bb * 16 + h) * 65536 + (size_t)dh * 1024 + s0] = v;
      }
    }
  }
}

// ---------------- flash attention v6: staging-free (m169 regime) + setprio ----------
// K/V per head = 256KB, L2-resident; per-tile working set 16KB, L1-resident and
// shared by the block's 4 waves. LDS staging of K/V was pure overhead (DMA + a
// per-tile __syncthreads that lockstep-coupled 4 independent waves). Dropped:
// fragment loads go straight to global at the UN-swizzled addresses (exact
// transcription of the verified staged decode -> identical MFMA operand layouts).
// ZERO barriers, zero LDS: waves run free; inactive tiles are skipped outright.
// Pairing (p,7-p) retained for uniform per-block compute (18 group-iters).
__global__ __launch_bounds__(256, 2) void attn_kernel(const unsigned short* __restrict__ Qb,
                                                      const unsigned short* __restrict__ Kb,
                                                      const unsigned short* __restrict__ VbT,
                                                      unsigned short* __restrict__ AOb) {
  const int tid = threadIdx.x;
  const int w = tid >> 6, lane = tid & 63;
  const int quad = lane >> 4, l16 = lane & 15;
  const int id = blockIdx.x;           // 0..511
  const int by = id >> 2;              // b*16 + h
  const int p = id & 3;                // pair (p, 7-p)
  const int bb = by >> 4, hh = by & 15;
  const int qlo = p * 128 + w * 32;
  const int qhi = (7 - p) * 128 + w * 32;
  const unsigned short* Qp = Qb + (size_t)by * 65536;
  const unsigned short* Kp = Kb + (size_t)by * 65536;
  const unsigned short* Vp = VbT + (size_t)by * 65536;

  // Q as B-operand of S^T = K.Q^T: B[k=d][n=query]; lane: n=l16, k=quad*8+j
  short8 bq[2][2][2];  // [g][qt][kh]
#pragma unroll
  for (int g = 0; g < 2; ++g)
#pragma unroll
    for (int qt = 0; qt < 2; ++qt)
#pragma unroll
      for (int kh = 0; kh < 2; ++kh)
        bq[g][qt][kh] = *(const short8*)(Qp + (size_t)((g ? qhi : qlo) + qt * 16 + l16) * 64 +
                                         kh * 32 + quad * 8);

  floatx4 o[2][2][4];   // [g][qt][dt]
  floatx4 ps[2][2];     // [g][qt] softmax denominators via ones-MFMA (rows=query)
#pragma unroll
  for (int g = 0; g < 2; ++g)
#pragma unroll
    for (int qt = 0; qt < 2; ++qt) {
      ps[g][qt] = (floatx4){0.f, 0.f, 0.f, 0.f};
#pragma unroll
      for (int dt = 0; dt < 4; ++dt) o[g][qt][dt] = (floatx4){0.f, 0.f, 0.f, 0.f};
    }

  short8 ones;
#pragma unroll
  for (int i = 0; i < 8; ++i) ones[i] = (short)0x3F80;  // bf16 1.0

  const int T = 16 - 2 * p;  // key tiles cover keys 0..(7-p)*128+127

  for (int t = 0; t < T; ++t) {
    const int n0 = t * 64;
    const bool alo = (n0 <= qlo + 31), ahi = (n0 <= qhi + 31);  // wave-uniform
    if (!(alo | ahi)) continue;

    // K fragments direct from global: A[m=key][k=dh]; 16B/lane, L1-shared by 4 waves
    short8 ak[4][2];
#pragma unroll
    for (int kt = 0; kt < 4; ++kt)
#pragma unroll
      for (int kh = 0; kh < 2; ++kh)
        ak[kt][kh] = *(const short8*)(Kp + (size_t)(n0 + kt * 16 + l16) * 64 +
                                      kh * 32 + quad * 8);
    union PaU { short8 v; uint32_t d[4]; };
    PaU pa[2][2][2];  // [g][qt][u]: P in PV A-layout (packed bf16)

    auto score = [&](int g, int qb) {
      const bool full = (n0 + 63 <= qb);  // wave-uniform
      __builtin_amdgcn_s_setprio(1);
#pragma unroll
      for (int kt = 0; kt < 4; ++kt)
#pragma unroll
        for (int qt = 0; qt < 2; ++qt) {
          floatx4 s = (floatx4){0.f, 0.f, 0.f, 0.f};
          s = __builtin_amdgcn_mfma_f32_16x16x32_bf16(ak[kt][0], bq[g][qt][0], s, 0, 0, 0);
          s = __builtin_amdgcn_mfma_f32_16x16x32_bf16(ak[kt][1], bq[g][qt][1], s, 0, 0, 0);
          float f[4];
          if (full) {
#pragma unroll
            for (int r = 0; r < 4; ++r)
              f[r] = exp2f(fmaf(s[r], 0.18033688f, -11.5415603f));  // exp(s/8-8)
          } else {
            const int query = qb + qt * 16 + l16;
#pragma unroll
            for (int r = 0; r < 4; ++r) {
              const int key = n0 + kt * 16 + quad * 4 + r;
              float e = exp2f(fmaf(s[r], 0.18033688f, -11.5415603f));
              f[r] = (key <= query) ? e : 0.0f;
            }
          }
          pa[g][qt][kt >> 1].d[(kt & 1) * 2 + 0] = pkbf(f[1], f[0]);
          pa[g][qt][kt >> 1].d[(kt & 1) * 2 + 1] = pkbf(f[3], f[2]);
        }
      // denominator: D[q][*] += sum_k P  (rows = query, matches o layout)
#pragma unroll
      for (int qt = 0; qt < 2; ++qt)
#pragma unroll
        for (int u = 0; u < 2; ++u)
          ps[g][qt] = __builtin_amdgcn_mfma_f32_16x16x32_bf16(pa[g][qt][u].v, ones, ps[g][qt], 0, 0, 0);
      __builtin_amdgcn_s_setprio(0);
    };
    if (alo) score(0, qlo);
    if (ahi) score(1, qhi);

    // PV: V^T fragments direct from global; B[k=key][n=dh].
    // h[0]: keys n0+u*32+quad*4..+3, h[1]: +16 — exact un-swizzled staged decode.
    __builtin_amdgcn_s_setprio(1);
#pragma unroll
    for (int dt = 0; dt < 4; ++dt) {
      const unsigned short* vrow = Vp + (size_t)(dt * 16 + l16) * 1024 + n0;
#pragma unroll
      for (int u = 0; u < 2; ++u) {
        union { short8 v8; ushort4 h[2]; } bv;
        bv.h[0] = *(const ushort4*)(vrow + u * 32 + quad * 4);
        bv.h[1] = *(const ushort4*)(vrow + u * 32 + 16 + quad * 4);
        if (alo) {
#pragma unroll
          for (int qt = 0; qt < 2; ++qt)
            o[0][qt][dt] = __builtin_amdgcn_mfma_f32_16x16x32_bf16(pa[0][qt][u].v, bv.v8, o[0][qt][dt], 0, 0, 0);
        }
        if (ahi) {
#pragma unroll
          for (int qt = 0; qt < 2; ++qt)
            o[1][qt][dt] = __builtin_amdgcn_mfma_f32_16x16x32_bf16(pa[1][qt][u].v, bv.v8, o[1][qt][dt], 0, 0, 0);
        }
      }
    }
    __builtin_amdgcn_s_setprio(0);
  }

  // epilogue: 1/l is in-lane (ps rows = query rows of o) — no shuffles
#pragma unroll
  for (int g = 0; g < 2; ++g) {
    const int qb = g ? qhi : qlo;
#pragma unroll
    for (int qt = 0; qt < 2; ++qt) {
      float inv[4];
#pragma unroll
      for (int r = 0; r < 4; ++r) inv[r] = 1.0f / ps[g][qt][r];
#pragma unroll
      for (int dt = 0; dt < 4; ++dt)
#pragma unroll
        for (int r = 0; r < 4; ++r) {
          int row = qb + qt * 16 + quad * 4 + r;
          AOb[(size_t)(bb * 1024 + row) * 1024 + hh * 64 + dt * 16 + l16] =
              f2bf(o[g][qt][dt][r] * inv[r]);
        }
    }
  }
}

extern "C" void kernel_launch(void* const* d_in, const int* in_sizes, int n_in,
                              void* d_out, int out_size, void* d_ws, size_t ws_size,
                              hipStream_t stream) {
  const float* x    = (const float*)d_in[0];
  // d_in[1] = causal mask: structure is known, unused
  const float* Wqkv = (const float*)d_in[2];
  const float* Wout = (const float*)d_in[3];
  float* out = (float*)d_out;

  // workspace layout (bf16 elements), total 88 MB
  unsigned short* xb    = (unsigned short*)d_ws;             // [8192,1024]
  unsigned short* WqkvT = xb    + (size_t)8 * 1024 * 1024;   // [3072,1024]
  unsigned short* WoutT = WqkvT + (size_t)3 * 1024 * 1024;   // [1024,1024]
  unsigned short* Qb    = WoutT + (size_t)1024 * 1024;       // [B,H,S,DH]
  unsigned short* Kb    = Qb    + (size_t)8 * 1024 * 1024;   // [B,H,S,DH]
  unsigned short* VbT   = Kb    + (size_t)8 * 1024 * 1024;   // [B,H,DH,S]
  unsigned short* AOb   = VbT   + (size_t)8 * 1024 * 1024;   // [8192,1024]

  prep_kernel<<<12288, 256, 0, stream>>>(x, xb, Wqkv, WqkvT, Wout, WoutT);
  gemm_bt_kernel<<<dim3(24, 64), 256, 0, stream>>>(xb, WqkvT, 3072, 0, Qb, Kb, VbT, nullptr);
  attn_kernel<<<512, 256, 0, stream>>>(Qb, Kb, VbT, AOb);
  gemm_bt_kernel<<<dim3(8, 64), 256, 0, stream>>>(AOb, WoutT, 1024, 1, nullptr, nullptr, nullptr, out);
}

// Round 7
// 220.229 us; speedup vs baseline: 1.2137x; 1.2137x over previous
//
#include <hip/hip_runtime.h>
#include <stdint.h>

// Problem constants: B=8, S=1024, D=1024, H=16, DH=64
typedef __attribute__((ext_vector_type(8))) short short8;
typedef __attribute__((ext_vector_type(4))) float floatx4;

__device__ __forceinline__ unsigned short f2bf(float f) {
  union { float f; uint32_t u; } v; v.f = f;
  uint32_t u = v.u;
  return (unsigned short)((u + 0x7FFFu + ((u >> 16) & 1u)) >> 16);  // RNE
}

__device__ __forceinline__ uint32_t fbits(float f) {
  union { float f; uint32_t u; } v; v.f = f; return v.u;
}
// pack two fp32 -> [bf16(hi):bf16(lo)] in ONE v_perm_b32 (truncating round)
__device__ __forceinline__ uint32_t pkbf(float hi, float lo) {
  return __builtin_amdgcn_perm(fbits(hi), fbits(lo), 0x07060302u);
}

// async global->LDS, 16B per lane; LDS dest = wave-uniform base + lane*16
__device__ __forceinline__ void gl_lds16(const void* g, void* l) {
  __builtin_amdgcn_global_load_lds((__attribute__((address_space(1))) void*)g,
                                   (__attribute__((address_space(3))) void*)l,
                                   16, 0, 0);
}

// ------- fused prep: cast x->bf16 (blocks 0..8191) + transpose both weights -------
__global__ __launch_bounds__(256) void prep_kernel(const float* __restrict__ x,
                                                   unsigned short* __restrict__ xb,
                                                   const float* __restrict__ Wqkv,
                                                   unsigned short* __restrict__ WqkvT,
                                                   const float* __restrict__ Wout,
                                                   unsigned short* __restrict__ WoutT) {
  __shared__ float tile[32][33];  // +1 pad (transpose branch only)
  int id = blockIdx.x;
  if (id < 8192) {
    int i = id * 256 + threadIdx.x;
    float4 v = ((const float4*)x)[i];
    ushort4 o;
    o.x = f2bf(v.x); o.y = f2bf(v.y); o.z = f2bf(v.z); o.w = f2bf(v.w);
    ((ushort4*)xb)[i] = o;
    return;
  }
  id -= 8192;                      // 0..4095
  int bx = id & 127, r0 = (id >> 7) * 32;
  const int R = 1024;
  const float* in; unsigned short* out; int C;
  if (bx < 96) { in = Wqkv; out = WqkvT; C = 3072; }
  else         { in = Wout; out = WoutT; C = 1024; bx -= 96; }
  int c0 = bx * 32;
  int tx = threadIdx.x & 31;
  int ty = threadIdx.x >> 5;  // 0..7
  for (int i = ty; i < 32; i += 8)
    tile[i][tx] = in[(size_t)(r0 + i) * C + c0 + tx];
  __syncthreads();
  for (int i = ty; i < 32; i += 8)
    out[(size_t)(c0 + i) * R + r0 + tx] = f2bf(tile[tx][i]);
}

// ---------------- GEMM C[M,N] = A[M,1024] * Bt[N,1024]^T  (bf16 in, fp32 acc) -------
// 128x128 tile, BK=64, double-buffered global_load_lds staging, XOR-swizzled
// chunks, LDS-bounce coalesced epilogue. Proven structure: ~61 us QKV,
// MfmaUtil ~35% = this structure's ceiling (m97-ladder). 2D grid dim3(N/128, 64):
// consecutive blocks walk N sharing one A-panel — measured FETCH 77MB; every
// swizzle attempt (R3/R4) increased FETCH (200MB) and regressed. Do not re-swizzle.
__global__ __launch_bounds__(256) void gemm_bt_kernel(const unsigned short* __restrict__ A,
                                                      const unsigned short* __restrict__ Bt,
                                                      int N, int mode,
                                                      unsigned short* __restrict__ qo,
                                                      unsigned short* __restrict__ ko,
                                                      unsigned short* __restrict__ vo,
                                                      float* __restrict__ fo) {
  const int Kd = 1024;
  __shared__ union {
    struct { unsigned short A[2][8192]; unsigned short B[2][8192]; } s;  // 4x16KB
    float cf[16384];          // epilogue bounce, fp32 (64KB)
    unsigned short ch[32768]; // epilogue bounce, bf16 (first 32KB)
  } sm;
  const int tid = threadIdx.x;
  const int w = tid >> 6, lane = tid & 63;
  const int quad = lane >> 4, l16 = lane & 15;
  const int l7 = l16 & 7;
  const int wm = w >> 1, wn = w & 1;
  const int m0 = blockIdx.y * 128, n0 = blockIdx.x * 128;
  const int tr = (mode == 0) && (n0 >= 2048);  // all-V block: compute C^T
  const int r8 = lane >> 3, ch = lane & 7;
  const int sw = (ch ^ r8) * 8;  // swizzled k-chunk (elements) for staging

  floatx4 acc[4][4];
#pragma unroll
  for (int i = 0; i < 4; ++i)
#pragma unroll
    for (int j = 0; j < 4; ++j)
      acc[i][j] = (floatx4){0.f, 0.f, 0.f, 0.f};

  auto stage = [&](int it, int buf) {
    const int k0 = it * 64;
#pragma unroll
    for (int i = 0; i < 4; ++i) {
      const int row = i * 32 + w * 8 + r8;  // row&7 == r8
      gl_lds16(A + (size_t)(m0 + row) * Kd + k0 + sw, (char*)&sm.s.A[buf][0] + i * 4096 + w * 1024);
      gl_lds16(Bt + (size_t)(n0 + row) * Kd + k0 + sw, (char*)&sm.s.B[buf][0] + i * 4096 + w * 1024);
    }
  };

  stage(0, 0);
  __syncthreads();

  for (int it = 0; it < 16; ++it) {
    const int buf = it & 1;
    if (it < 15) stage(it + 1, buf ^ 1);  // async DMA, overlapped with compute(it)
    const char* Ab = (const char*)&sm.s.A[buf][0];
    const char* Bb = (const char*)&sm.s.B[buf][0];
#pragma unroll
    for (int half = 0; half < 2; ++half) {
      short8 af[4], bf[4];
#pragma unroll
      for (int i = 0; i < 4; ++i)
        af[i] = *(const short8*)(Ab + (wm * 64 + i * 16 + l16) * 128 +
                                 (((half << 2) | quad) ^ l7) * 16);
#pragma unroll
      for (int j = 0; j < 4; ++j)
        bf[j] = *(const short8*)(Bb + (wn * 64 + j * 16 + l16) * 128 +
                                 (((half << 2) | quad) ^ l7) * 16);
      if (!tr) {
#pragma unroll
        for (int i = 0; i < 4; ++i)
#pragma unroll
          for (int j = 0; j < 4; ++j)
            acc[i][j] = __builtin_amdgcn_mfma_f32_16x16x32_bf16(af[i], bf[j], acc[i][j], 0, 0, 0);
      } else {
#pragma unroll
        for (int p = 0; p < 4; ++p)
#pragma unroll
          for (int q = 0; q < 4; ++q)
            acc[p][q] = __builtin_amdgcn_mfma_f32_16x16x32_bf16(bf[p], af[q], acc[p][q], 0, 0, 0);
      }
    }
    __syncthreads();  // drains stage(it+1) DMA + guards buf reuse
  }

  // ---- LDS-bounce epilogue ----  C/D layout: col = lane&15, row = quad*4 + r
  if (mode == 1) {
    float* Cs = sm.cf;
#pragma unroll
    for (int i = 0; i < 4; ++i)
#pragma unroll
      for (int j = 0; j < 4; ++j)
#pragma unroll
        for (int r = 0; r < 4; ++r) {
          int row = wm * 64 + i * 16 + quad * 4 + r;
          int col = wn * 64 + j * 16 + l16;
          Cs[row * 128 + (col ^ ((row & 7) << 2))] = acc[i][j][r];
        }
    __syncthreads();
#pragma unroll
    for (int c = 0; c < 16; ++c) {
      int idx = c * 256 + tid;
      int row = idx >> 5, fc = idx & 31;
      float4 v = *(const float4*)&sm.cf[row * 128 + ((fc ^ (row & 7)) << 2)];
      *(float4*)&fo[(size_t)(m0 + row) * N + n0 + fc * 4] = v;
    }
  } else {
    unsigned short* Cs = sm.ch;
    if (!tr) {
#pragma unroll
      for (int i = 0; i < 4; ++i)
#pragma unroll
        for (int j = 0; j < 4; ++j)
#pragma unroll
          for (int r = 0; r < 4; ++r) {
            int row = wm * 64 + i * 16 + quad * 4 + r;
            int col = wn * 64 + j * 16 + l16;
            Cs[row * 128 + (col ^ ((row & 7) << 3))] = f2bf(acc[i][j][r]);
          }
    } else {
#pragma unroll
      for (int p = 0; p < 4; ++p)
#pragma unroll
        for (int q = 0; q < 4; ++q)
#pragma unroll
          for (int r = 0; r < 4; ++r) {
            int row = wn * 64 + p * 16 + quad * 4 + r;  // n-local
            int col = wm * 64 + q * 16 + l16;           // m-local
            Cs[row * 128 + (col ^ ((row & 7) << 3))] = f2bf(acc[p][q][r]);
          }
    }
    __syncthreads();
    unsigned short* dst0 = (n0 < 1024) ? qo : ko;  // used only when !tr
#pragma unroll
    for (int c = 0; c < 8; ++c) {
      int idx = c * 256 + tid;
      int row = idx >> 4, lc = idx & 15;
      short8 v = *(const short8*)&sm.ch[row * 128 + ((lc ^ (row & 7)) << 3)];
      int col = lc * 8;
      if (!tr) {
        int m = m0 + row, n = n0 + col;
        int h = (n & 1023) >> 6, dh = n & 63;
        int bb = m >> 10, s = m & 1023;
        *(short8*)&dst0[(size_t)(bb * 16 + h) * 65536 + (size_t)s * 64 + dh] = v;
      } else {
        int n = n0 + row, m = m0 + col;
        int h = (n & 1023) >> 6, dh = n & 63;
        int bb = m >> 10, s0 = m & 1023;
        *(short8*)&vo[(size_t)(bb * 16 + h) * 65536 + (size_t)dh * 1024 + s0] = v;
      }
    }
  }
}

// ---------------- flash attention v7: staged (reverted) + KVBLK=128 -----------------
// R6 lesson: direct-global fragment loads are scattered gathers (16 rows/instr) —
// staging via gl_lds is the coalescer; keep it. Delta vs the 220.3us v5: stage
// 128 keys per buffer (two 64-key halves, side by side, each in the VERBATIM v5
// layout+swizzle) and run both halves between ONE barrier pair -> half the
// per-tile __syncthreads/vmcnt drains, same MFMA count, same 64-key masking
// granularity, same registers. LDS 64KB -> still 2 blocks/CU at (256,2).
// Staged coverage exact: T=8-p tiles cover keys 0..(8-p)*128-1 = pair's max need.
__global__ __launch_bounds__(256, 2) void attn_kernel(const unsigned short* __restrict__ Qb,
                                                      const unsigned short* __restrict__ Kb,
                                                      const unsigned short* __restrict__ VbT,
                                                      unsigned short* __restrict__ AOb) {
  __shared__ unsigned short Kt[2][8192];  // [buf][2 key-halves][64 keys][64 dh]
  __shared__ unsigned short Vt[2][8192];  // [buf][2 key-halves][64 dh][64 keys]
  const int tid = threadIdx.x;
  const int w = tid >> 6, lane = tid & 63;
  const int quad = lane >> 4, l16 = lane & 15;
  const int l7 = l16 & 7;
  const int id = blockIdx.x;           // 0..511
  const int by = id >> 2;              // b*16 + h
  const int p = id & 3;                // pair (p, 7-p)
  const int bb = by >> 4, hh = by & 15;
  const int qlo = p * 128 + w * 32;
  const int qhi = (7 - p) * 128 + w * 32;
  const unsigned short* Qp = Qb + (size_t)by * 65536;
  const unsigned short* Kp = Kb + (size_t)by * 65536;
  const unsigned short* Vp = VbT + (size_t)by * 65536;

  // Q as B-operand of S^T = K.Q^T: B[k=d][n=query]; lane: n=l16, k=quad*8+j
  short8 bq[2][2][2];  // [g][qt][kh]
#pragma unroll
  for (int g = 0; g < 2; ++g)
#pragma unroll
    for (int qt = 0; qt < 2; ++qt)
#pragma unroll
      for (int kh = 0; kh < 2; ++kh)
        bq[g][qt][kh] = *(const short8*)(Qp + (size_t)((g ? qhi : qlo) + qt * 16 + l16) * 64 +
                                         kh * 32 + quad * 8);

  floatx4 o[2][2][4];   // [g][qt][dt]
  floatx4 ps[2][2];     // [g][qt] softmax denominators via ones-MFMA (rows=query)
#pragma unroll
  for (int g = 0; g < 2; ++g)
#pragma unroll
    for (int qt = 0; qt < 2; ++qt) {
      ps[g][qt] = (floatx4){0.f, 0.f, 0.f, 0.f};
#pragma unroll
      for (int dt = 0; dt < 4; ++dt) o[g][qt][dt] = (floatx4){0.f, 0.f, 0.f, 0.f};
    }

  short8 ones;
#pragma unroll
  for (int i = 0; i < 8; ++i) ones[i] = (short)0x3F80;  // bf16 1.0

  const int T = 8 - p;  // 128-key tiles cover keys 0..(8-p)*128-1
  const int r8 = lane >> 3, ch = lane & 7;
  const int sw8 = (ch ^ r8) * 8;  // swizzled global chunk (elements)

  auto stage = [&](int t, int buf) {
    const int k0 = t * 128;
#pragma unroll
    for (int kv = 0; kv < 2; ++kv)
#pragma unroll
      for (int i = 0; i < 2; ++i) {
        const int c = w * 2 + i;          // 8-row group 0..7 within the half
        const int row = c * 8 + r8;
        gl_lds16(Kp + (size_t)(k0 + kv * 64 + row) * 64 + sw8,
                 (char*)&Kt[buf][0] + kv * 8192 + c * 1024);
        gl_lds16(Vp + (size_t)row * 1024 + k0 + kv * 64 + sw8,
                 (char*)&Vt[buf][0] + kv * 8192 + c * 1024);
      }
  };

  stage(0, 0);
  __syncthreads();

  for (int t = 0; t < T; ++t) {
    const int buf = t & 1;
    if (t + 1 < T) stage(t + 1, buf ^ 1);  // async DMA, overlapped with compute
#pragma unroll
    for (int kv = 0; kv < 2; ++kv) {
      const int n0 = t * 128 + kv * 64;
      const bool alo = (n0 <= qlo + 31), ahi = (n0 <= qhi + 31);  // wave-uniform
      if (!(alo | ahi)) continue;
      const char* kbase = (const char*)&Kt[buf][0] + kv * 8192;
      const char* vbase = (const char*)&Vt[buf][0] + kv * 8192;
      short8 ak[4][2];
#pragma unroll
      for (int kt = 0; kt < 4; ++kt)
#pragma unroll
        for (int kh = 0; kh < 2; ++kh)
          ak[kt][kh] = *(const short8*)(kbase + (kt * 16 + l16) * 128 +
                                        (((kh << 2) | quad) ^ l7) * 16);
      union PaU { short8 v; uint32_t d[4]; };
      PaU pa[2][2][2];  // [g][qt][u]: P in PV A-layout (packed bf16)

      auto score = [&](int g, int qb) {
        const bool full = (n0 + 63 <= qb);  // wave-uniform
        __builtin_amdgcn_s_setprio(1);
#pragma unroll
        for (int kt = 0; kt < 4; ++kt)
#pragma unroll
          for (int qt = 0; qt < 2; ++qt) {
            floatx4 s = (floatx4){0.f, 0.f, 0.f, 0.f};
            s = __builtin_amdgcn_mfma_f32_16x16x32_bf16(ak[kt][0], bq[g][qt][0], s, 0, 0, 0);
            s = __builtin_amdgcn_mfma_f32_16x16x32_bf16(ak[kt][1], bq[g][qt][1], s, 0, 0, 0);
            float f[4];
            if (full) {
#pragma unroll
              for (int r = 0; r < 4; ++r)
                f[r] = exp2f(fmaf(s[r], 0.18033688f, -11.5415603f));  // exp(s/8-8)
            } else {
              const int query = qb + qt * 16 + l16;
#pragma unroll
              for (int r = 0; r < 4; ++r) {
                const int key = n0 + kt * 16 + quad * 4 + r;
                float e = exp2f(fmaf(s[r], 0.18033688f, -11.5415603f));
                f[r] = (key <= query) ? e : 0.0f;
              }
            }
            pa[g][qt][kt >> 1].d[(kt & 1) * 2 + 0] = pkbf(f[1], f[0]);
            pa[g][qt][kt >> 1].d[(kt & 1) * 2 + 1] = pkbf(f[3], f[2]);
          }
        // denominator: D[q][*] += sum_k P  (rows = query, matches o layout)
#pragma unroll
        for (int qt = 0; qt < 2; ++qt)
#pragma unroll
          for (int u = 0; u < 2; ++u)
            ps[g][qt] = __builtin_amdgcn_mfma_f32_16x16x32_bf16(pa[g][qt][u].v, ones, ps[g][qt], 0, 0, 0);
        __builtin_amdgcn_s_setprio(0);
      };
      if (alo) score(0, qlo);
      if (ahi) score(1, qhi);

      // PV: bv fragments loaded once, shared by both groups
      __builtin_amdgcn_s_setprio(1);
#pragma unroll
      for (int dt = 0; dt < 4; ++dt) {
        const int row128 = (dt * 16 + l16) * 128;
#pragma unroll
        for (int u = 0; u < 2; ++u) {
          union { short8 v8; ushort4 h[2]; } bv;
          bv.h[0] = *(const ushort4*)(vbase + row128 +
                                      (((u << 2) | (quad >> 1)) ^ l7) * 16 + (quad & 1) * 8);
          bv.h[1] = *(const ushort4*)(vbase + row128 +
                                      (((u << 2) | 2 | (quad >> 1)) ^ l7) * 16 + (quad & 1) * 8);
          if (alo) {
#pragma unroll
            for (int qt = 0; qt < 2; ++qt)
              o[0][qt][dt] = __builtin_amdgcn_mfma_f32_16x16x32_bf16(pa[0][qt][u].v, bv.v8, o[0][qt][dt], 0, 0, 0);
          }
          if (ahi) {
#pragma unroll
            for (int qt = 0; qt < 2; ++qt)
              o[1][qt][dt] = __builtin_amdgcn_mfma_f32_16x16x32_bf16(pa[1][qt][u].v, bv.v8, o[1][qt][dt], 0, 0, 0);
          }
        }
      }
      __builtin_amdgcn_s_setprio(0);
    }
    __syncthreads();  // drains stage(t+1) DMA + guards buf reuse
  }

  // epilogue: 1/l is in-lane (ps rows = query rows of o) — no shuffles
#pragma unroll
  for (int g = 0; g < 2; ++g) {
    const int qb = g ? qhi : qlo;
#pragma unroll
    for (int qt = 0; qt < 2; ++qt) {
      float inv[4];
#pragma unroll
      for (int r = 0; r < 4; ++r) inv[r] = 1.0f / ps[g][qt][r];
#pragma unroll
      for (int dt = 0; dt < 4; ++dt)
#pragma unroll
        for (int r = 0; r < 4; ++r) {
          int row = qb + qt * 16 + quad * 4 + r;
          AOb[(size_t)(bb * 1024 + row) * 1024 + hh * 64 + dt * 16 + l16] =
              f2bf(o[g][qt][dt][r] * inv[r]);
        }
    }
  }
}

extern "C" void kernel_launch(void* const* d_in, const int* in_sizes, int n_in,
                              void* d_out, int out_size, void* d_ws, size_t ws_size,
                              hipStream_t stream) {
  const float* x    = (const float*)d_in[0];
  // d_in[1] = causal mask: structure is known, unused
  const float* Wqkv = (const float*)d_in[2];
  const float* Wout = (const float*)d_in[3];
  float* out = (float*)d_out;

  // workspace layout (bf16 elements), total 88 MB
  unsigned short* xb    = (unsigned short*)d_ws;             // [8192,1024]
  unsigned short* WqkvT = xb    + (size_t)8 * 1024 * 1024;   // [3072,1024]
  unsigned short* WoutT = WqkvT + (size_t)3 * 1024 * 1024;   // [1024,1024]
  unsigned short* Qb    = WoutT + (size_t)1024 * 1024;       // [B,H,S,DH]
  unsigned short* Kb    = Qb    + (size_t)8 * 1024 * 1024;   // [B,H,S,DH]
  unsigned short* VbT   = Kb    + (size_t)8 * 1024 * 1024;   // [B,H,DH,S]
  unsigned short* AOb   = VbT   + (size_t)8 * 1024 * 1024;   // [8192,1024]

  prep_kernel<<<12288, 256, 0, stream>>>(x, xb, Wqkv, WqkvT, Wout, WoutT);
  gemm_bt_kernel<<<dim3(24, 64), 256, 0, stream>>>(xb, WqkvT, 3072, 0, Qb, Kb, VbT, nullptr);
  attn_kernel<<<512, 256, 0, stream>>>(Qb, Kb, VbT, AOb);
  gemm_bt_kernel<<<dim3(8, 64), 256, 0, stream>>>(AOb, WoutT, 1024, 1, nullptr, nullptr, nullptr, out);
}